// Round 3
// baseline (190.530 us; speedup 1.0000x reference)
//
#include <hip/hip_runtime.h>
#include <hip/hip_bf16.h>
#include <math.h>

typedef __hip_bfloat16 bf16;
typedef __bf16 bf16x8 __attribute__((ext_vector_type(8)));
typedef float  f32x4  __attribute__((ext_vector_type(4)));

#define NB 8
#define SL 1024
#define DD 256
#define NF 11
#define RPB 8

#define AS_G __attribute__((address_space(1)))
#define AS_L __attribute__((address_space(3)))

// ---------- fragment loaders ----------
__device__ __forceinline__ bf16x8 ldfrag(const bf16* p) {
  return *reinterpret_cast<const bf16x8*>(p);
}
__device__ __forceinline__ bf16x8 ldfrag(const float* p) {
  const float4 a = *reinterpret_cast<const float4*>(p);
  const float4 b = *reinterpret_cast<const float4*>(p + 4);
  bf16x8 r;
  r[0] = (__bf16)a.x; r[1] = (__bf16)a.y; r[2] = (__bf16)a.z; r[3] = (__bf16)a.w;
  r[4] = (__bf16)b.x; r[5] = (__bf16)b.y; r[6] = (__bf16)b.z; r[7] = (__bf16)b.w;
  return r;
}
__device__ __forceinline__ unsigned short us(float f) {
  bf16 h = __float2bfloat16(f);
  return *reinterpret_cast<unsigned short*>(&h);
}
__device__ __forceinline__ float tanh_fast(float x) {
  return 1.f - 2.f / (__expf(2.f * x) + 1.f);
}

// ---------- stage R rows x 64 k into XOR-swizzled LDS ----------
// f32 source: sync VGPR convert
template<int R>
__device__ __forceinline__ void stage_t(const float* __restrict__ g, int ld,
                                        bf16* __restrict__ s, int tid) {
#pragma unroll
  for (int it = 0; it < R / 32; ++it) {
    const int cid = it * 256 + tid;
    const int row = cid >> 3, c16 = cid & 7;
    bf16x8 v = ldfrag(g + (size_t)row * ld + c16 * 8);
    *reinterpret_cast<bf16x8*>(s + row * 64 + ((c16 ^ (row & 7)) << 3)) = v;
  }
}
// bf16 source: async global_load_lds, swizzle folded into source addr
template<int R>
__device__ __forceinline__ void stage_t(const bf16* __restrict__ g, int ld,
                                        bf16* __restrict__ s, int tid) {
  const int wbase = tid & ~63;
#pragma unroll
  for (int it = 0; it < R / 32; ++it) {
    const int cid = it * 256 + tid;
    const int row = cid >> 3, sc = cid & 7;
    const int c16 = sc ^ (row & 7);
    const bf16* src = g + (size_t)row * ld + c16 * 8;
    bf16* dst = s + (size_t)(it * 256 + wbase) * 8;
    __builtin_amdgcn_global_load_lds((const AS_G void*)src, (AS_L void*)dst, 16, 0, 0);
  }
}
// 16 rows x 64: only 2 waves participate
__device__ __forceinline__ void stage16(const bf16* __restrict__ g, int ld,
                                        bf16* __restrict__ s, int tid) {
  if (tid < 128) {
    const int wbase = tid & ~63;
    const int row = tid >> 3, sc = tid & 7;
    const int c16 = sc ^ (row & 7);
    const bf16* src = g + (size_t)row * ld + c16 * 8;
    bf16* dst = s + (size_t)wbase * 8;
    __builtin_amdgcn_global_load_lds((const AS_G void*)src, (AS_L void*)dst, 16, 0, 0);
  }
}

// ---------- compute: 128x128 tile, 4 waves (2x2), each wave 64x64 ----------
__device__ __forceinline__ void compute_128x128(const bf16* __restrict__ sA,
                                                const bf16* __restrict__ sB,
                                                int lane, int wave, f32x4 acc[4][4]) {
  const int n15 = lane & 15, quad = lane >> 4;
  const int wr = (wave >> 1) << 6, wc = (wave & 1) << 6;
#pragma unroll
  for (int kc = 0; kc < 2; ++kc) {
    const int c16 = kc * 4 + quad;
    bf16x8 aF[4], bF[4];
#pragma unroll
    for (int t = 0; t < 4; ++t) {
      const int ra = wr + t * 16 + n15;
      aF[t] = *reinterpret_cast<const bf16x8*>(sA + ra * 64 + ((c16 ^ (ra & 7)) << 3));
      const int rb = wc + t * 16 + n15;
      bF[t] = *reinterpret_cast<const bf16x8*>(sB + rb * 64 + ((c16 ^ (rb & 7)) << 3));
    }
#pragma unroll
    for (int ti = 0; ti < 4; ++ti)
#pragma unroll
      for (int tj = 0; tj < 4; ++tj)
        acc[ti][tj] = __builtin_amdgcn_mfma_f32_16x16x32_bf16(aF[ti], bF[tj], acc[ti][tj], 0, 0, 0);
  }
}

// ---------- compute: 64x128 tile, 4 waves (2x2), each wave 32x64 ----------
__device__ __forceinline__ void compute_64x128b(const bf16* __restrict__ sA,
                                                const bf16* __restrict__ sB,
                                                int lane, int wave, f32x4 acc[2][4]) {
  const int n15 = lane & 15, quad = lane >> 4;
  const int wr = (wave >> 1) << 5, wc = (wave & 1) << 6;
#pragma unroll
  for (int kc = 0; kc < 2; ++kc) {
    const int c16 = kc * 4 + quad;
    bf16x8 aF[2], bF[4];
#pragma unroll
    for (int t = 0; t < 2; ++t) {
      const int ra = wr + t * 16 + n15;
      aF[t] = *reinterpret_cast<const bf16x8*>(sA + ra * 64 + ((c16 ^ (ra & 7)) << 3));
    }
#pragma unroll
    for (int t = 0; t < 4; ++t) {
      const int rb = wc + t * 16 + n15;
      bF[t] = *reinterpret_cast<const bf16x8*>(sB + rb * 64 + ((c16 ^ (rb & 7)) << 3));
    }
#pragma unroll
    for (int ti = 0; ti < 2; ++ti)
#pragma unroll
      for (int tj = 0; tj < 4; ++tj)
        acc[ti][tj] = __builtin_amdgcn_mfma_f32_16x16x32_bf16(aF[ti], bF[tj], acc[ti][tj], 0, 0, 0);
  }
}

// ---------- compute: 16x256 tile, 4 waves (1x4), each wave 16x64 ----------
__device__ __forceinline__ void compute_16x256(const bf16* __restrict__ sA,
                                               const bf16* __restrict__ sB,
                                               int lane, int wave, f32x4 acc[4]) {
  const int n15 = lane & 15, quad = lane >> 4;
  const int wc = wave << 6;
#pragma unroll
  for (int kc = 0; kc < 2; ++kc) {
    const int c16 = kc * 4 + quad;
    bf16x8 aF, bF[4];
    {
      const int ra = n15;
      aF = *reinterpret_cast<const bf16x8*>(sA + ra * 64 + ((c16 ^ (ra & 7)) << 3));
    }
#pragma unroll
    for (int t = 0; t < 4; ++t) {
      const int rb = wc + t * 16 + n15;
      bF[t] = *reinterpret_cast<const bf16x8*>(sB + rb * 64 + ((c16 ^ (rb & 7)) << 3));
    }
#pragma unroll
    for (int tj = 0; tj < 4; ++tj)
      acc[tj] = __builtin_amdgcn_mfma_f32_16x16x32_bf16(aF, bF[tj], acc[tj], 0, 0, 0);
  }
}

// ---------- GEMM drivers: single-buffered (32KB-class LDS, m97 structure) ----------
template<typename TA, typename TB>
__device__ __forceinline__ void gemm_128x128(const TA* __restrict__ A, int lda,
                                             const TB* __restrict__ B, int ldb, int K,
                                             bf16* s, int tid, f32x4 acc[4][4]) {
  const int lane = tid & 63, wave = tid >> 6;
  for (int k0 = 0; k0 < K; k0 += 64) {
    stage_t<128>(A + k0, lda, s, tid);
    stage_t<128>(B + k0, ldb, s + 8192, tid);
    __syncthreads();
    compute_128x128(s, s + 8192, lane, wave, acc);
    __syncthreads();
  }
}

template<typename TA, typename TB>
__device__ __forceinline__ void gemm_64x128(const TA* __restrict__ A, int lda,
                                            const TB* __restrict__ B, int ldb, int K,
                                            bf16* s, int tid, f32x4 acc[2][4]) {
  const int lane = tid & 63, wave = tid >> 6;
  for (int k0 = 0; k0 < K; k0 += 64) {
    stage_t<64>(A + k0, lda, s, tid);
    stage_t<128>(B + k0, ldb, s + 4096, tid);
    __syncthreads();
    compute_64x128b(s, s + 4096, lane, wave, acc);
    __syncthreads();
  }
}

__device__ __forceinline__ float wred_sum(float v) {
#pragma unroll
  for (int o = 32; o > 0; o >>= 1) v += __shfl_xor(v, o, 64);
  return v;
}

// ---------- K0: k_fawc — feature-affinity softmax (blocks<1024) + Wc (blocks>=1024) ----
__global__ __launch_bounds__(256) void k_fawc(const float* __restrict__ x,
                                              const float* __restrict__ fi_g,
                                              const int* __restrict__ lens,
                                              const float* __restrict__ wfc,
                                              const float* __restrict__ wvs,
                                              bf16* __restrict__ fa,
                                              float* __restrict__ Wc)
{
  __shared__ __align__(16) float sx[SL * NF];
  __shared__ float sredS[4][RPB];
  const int tid = threadIdx.x, wave = tid >> 6;
  const int bid = blockIdx.x;
  if (bid >= NB * 128) {
    // Wc = wfc @ wvs ; 4 output rows per block
    const int o0 = (bid - NB * 128) * 4, m = tid;
    const float* f0 = wfc + (size_t)o0 * DD;
    float a0 = 0.f, a1 = 0.f, a2 = 0.f, a3 = 0.f;
#pragma unroll 8
    for (int i = 0; i < DD; ++i) {
      const float wv = wvs[(size_t)i * DD + m];
      a0 += f0[i] * wv;
      a1 += f0[DD + i] * wv;
      a2 += f0[2 * DD + i] * wv;
      a3 += f0[3 * DD + i] * wv;
    }
    Wc[(size_t)(o0 + 0) * DD + m] = a0;
    Wc[(size_t)(o0 + 1) * DD + m] = a1;
    Wc[(size_t)(o0 + 2) * DD + m] = a2;
    Wc[(size_t)(o0 + 3) * DD + m] = a3;
    return;
  }
  const int b  = bid >> 7;
  const int i0 = (bid & 127) * RPB;
  {
    const float4* src = reinterpret_cast<const float4*>(x + (size_t)b * SL * NF);
    float4* dst = reinterpret_cast<float4*>(sx);
#pragma unroll
    for (int it = 0; it < 11; ++it) dst[it * 256 + tid] = src[it * 256 + tid];
  }
  float fiv[NF];
#pragma unroll
  for (int f = 0; f < NF; ++f) fiv[f] = fi_g[f];
  const int len = lens[b];
  __syncthreads();
  float xi[RPB][NF];
#pragma unroll
  for (int i = 0; i < RPB; ++i)
#pragma unroll
    for (int f = 0; f < NF; ++f) xi[i][f] = sx[(i0 + i) * NF + f];
  float e[RPB][4];
  float ps[RPB];
#pragma unroll
  for (int i = 0; i < RPB; ++i) ps[i] = 0.f;
#pragma unroll
  for (int t = 0; t < 4; ++t) {
    const int j = tid + t * 256;
    const bool valid = (t < 2) || (j < len);
    float xj[NF];
#pragma unroll
    for (int f = 0; f < NF; ++f) xj[f] = sx[j * NF + f];
#pragma unroll
    for (int i = 0; i < RPB; ++i) {
      float a = 0.f;
#pragma unroll
      for (int f = 0; f < NF; ++f) a += fabsf(xi[i][f] - xj[f]) * fiv[f];
      float ev = valid ? __expf(a) : 0.f;
      e[i][t] = ev;
      ps[i] += ev;
    }
  }
#pragma unroll
  for (int i = 0; i < RPB; ++i) {
    float wsv = wred_sum(ps[i]);
    if ((tid & 63) == 0) sredS[wave][i] = wsv;
  }
  __syncthreads();
  bf16* out = fa + (size_t)b * SL * SL + (size_t)i0 * SL;
#pragma unroll
  for (int i = 0; i < RPB; ++i) {
    const float inv = 1.f / (sredS[0][i] + sredS[1][i] + sredS[2][i] + sredS[3][i]);
#pragma unroll
    for (int t = 0; t < 4; ++t)
      out[(size_t)i * SL + tid + t * 256] = __float2bfloat16(e[i][t] * inv);
  }
}

// ---------- K1: 5 projections straight from f32 inputs ----------
__global__ __launch_bounds__(256) void k_proj(
    const float* __restrict__ q, const float* __restrict__ k, const float* __restrict__ v,
    const float* __restrict__ wqs, const float* __restrict__ wks, const float* __restrict__ Wc,
    const float* __restrict__ wqs2, const float* __restrict__ wks2,
    bf16* __restrict__ qq, bf16* __restrict__ kk,
    bf16* __restrict__ vpwt, bf16* __restrict__ q2t, bf16* __restrict__ k2t)
{
  __shared__ bf16 smem[16384];   // 32KB single-buffer
  const int tid = threadIdx.x, lane = tid & 63, wave = tid >> 6;
  const int z = blockIdx.z;
  const float* A = (z == 2) ? v : ((z == 1 || z == 4) ? k : q);
  const float* W = (z == 0) ? wqs : (z == 1) ? wks : (z == 2) ? Wc : (z == 3) ? wqs2 : wks2;
  const int rowBase = blockIdx.x * 128;
  const int colBase = blockIdx.y * 128;
  f32x4 acc[4][4] = {};
  gemm_128x128(A + (size_t)rowBase * DD, DD, W + (size_t)colBase * DD, DD, DD, smem, tid, acc);
  const int n15 = lane & 15, quad = lane >> 4;
  const int wr = (wave >> 1) << 6, wc = (wave & 1) << 6;
  if (z <= 1) {
    bf16* O = (z == 0) ? qq : kk;
#pragma unroll
    for (int ti = 0; ti < 4; ++ti)
#pragma unroll
      for (int tj = 0; tj < 4; ++tj)
#pragma unroll
        for (int r = 0; r < 4; ++r) {
          int row = rowBase + wr + ti * 16 + quad * 4 + r;
          int col = colBase + wc + tj * 16 + n15;
          O[(size_t)row * 512 + col] = __float2bfloat16(acc[ti][tj][r]);
        }
  } else {
    bf16* O = (z == 2) ? vpwt : (z == 3) ? q2t : k2t;
    const int bb = rowBase >> 10, rowInB = rowBase & 1023;
#pragma unroll
    for (int ti = 0; ti < 4; ++ti)
#pragma unroll
      for (int tj = 0; tj < 4; ++tj) {
        int l0  = rowInB + wr + ti * 16 + quad * 4;
        int col = colBase + wc + tj * 16 + n15;
        ushort4 pk = make_ushort4(us(acc[ti][tj][0]), us(acc[ti][tj][1]),
                                  us(acc[ti][tj][2]), us(acc[ti][tj][3]));
        *reinterpret_cast<ushort4*>(&O[((size_t)bb * DD + col) * SL + l0]) = pk;
      }
  }
}

// ---------- K2: q2f/k2f = fa @ {q2,k2} -> qq/kk cols 256..511 (64-row tiles) ----------
__global__ __launch_bounds__(256) void k_famul(const bf16* __restrict__ fa,
                                               const bf16* __restrict__ q2t,
                                               const bf16* __restrict__ k2t,
                                               const int* __restrict__ lens,
                                               bf16* __restrict__ qq,
                                               bf16* __restrict__ kk)
{
  __shared__ bf16 smem[12288];   // 8KB A + 16KB B
  const int tid = threadIdx.x, lane = tid & 63, wave = tid >> 6;
  // grid 512 flat; swizzle so batch ~ XCD
  const int flat = blockIdx.x;
  const int lid  = (flat & 7) * 64 + (flat >> 3);
  const int bx = lid & 15, by = (lid >> 4) & 1;
  const int which = (lid >> 5) & 1, b = lid >> 6;
  const int iBase = bx * 64, dBase = by * 128;
  const int Keff = (lens[b] + 63) & ~63;
  const bf16* A  = fa + (size_t)b * SL * SL + (size_t)iBase * SL;
  const bf16* Bm = (which ? k2t : q2t) + (size_t)b * DD * SL + (size_t)dBase * SL;
  f32x4 acc[2][4] = {};
  gemm_64x128(A, SL, Bm, SL, Keff, smem, tid, acc);
  bf16* O = (which ? kk : qq) + (size_t)b * SL * 512 + 256;
  const int n15 = lane & 15, quad = lane >> 4;
  const int wr = (wave >> 1) << 5, wc = (wave & 1) << 6;
#pragma unroll
  for (int ti = 0; ti < 2; ++ti)
#pragma unroll
    for (int tj = 0; tj < 4; ++tj)
#pragma unroll
      for (int r = 0; r < 4; ++r)
        O[(size_t)(iBase + wr + ti * 16 + quad * 4 + r) * 512 +
          dBase + wc + tj * 16 + n15] = __float2bfloat16(acc[ti][tj][r]);
}

// ---------- K3: attn = tanh(mask(qq.kk^T/16)), K=512 (64-row tiles); dual store ----------
__global__ __launch_bounds__(256) void k_attn(const bf16* __restrict__ qq,
                                              const bf16* __restrict__ kk,
                                              const int* __restrict__ lens,
                                              float* __restrict__ attn_f32,
                                              bf16* __restrict__ attn_b16)
{
  __shared__ bf16 smem[12288];
  const int tid = threadIdx.x, lane = tid & 63, wave = tid >> 6;
  // grid 1024 flat; swizzle so batch ~ XCD
  const int flat = blockIdx.x;
  const int lid  = (flat & 7) * 128 + (flat >> 3);
  const int bx = lid & 15, by = (lid >> 4) & 7, b = lid >> 7;
  const int iBase = bx * 64, jBase = by * 128;
  const int len = lens[b];
  if (jBase >= len) {
    // fully masked 64x128 tile: write zeros, no GEMM
    const int r = tid >> 2, c0 = (tid & 3) * 32;
    float* pf = attn_f32 + (size_t)b * SL * SL + (size_t)(iBase + r) * SL + jBase + c0;
    bf16*  pb = attn_b16 + (size_t)b * SL * SL + (size_t)(iBase + r) * SL + jBase + c0;
    const float4 z4 = make_float4(0.f, 0.f, 0.f, 0.f);
    const uint4  zb = make_uint4(0u, 0u, 0u, 0u);
#pragma unroll
    for (int i = 0; i < 8; ++i) *reinterpret_cast<float4*>(pf + i * 4) = z4;
#pragma unroll
    for (int i = 0; i < 4; ++i) *reinterpret_cast<uint4*>(pb + i * 8) = zb;
    return;
  }
  f32x4 acc[2][4] = {};
  gemm_64x128(qq + ((size_t)b * SL + iBase) * 512, 512,
              kk + ((size_t)b * SL + jBase) * 512, 512, 512, smem, tid, acc);
  const int n15 = lane & 15, quad = lane >> 4;
  const int wr = (wave >> 1) << 5, wc = (wave & 1) << 6;
#pragma unroll
  for (int ti = 0; ti < 2; ++ti)
#pragma unroll
    for (int tj = 0; tj < 4; ++tj)
#pragma unroll
      for (int r = 0; r < 4; ++r) {
        int i = iBase + wr + ti * 16 + quad * 4 + r;
        int j = jBase + wc + tj * 16 + n15;
        float vv = (j < len) ? tanh_fast(acc[ti][tj][r] * (1.f / 16.f)) : 0.f;
        size_t idx = (size_t)b * SL * SL + (size_t)i * SL + j;
        attn_f32[idx] = vv;
        attn_b16[idx] = __float2bfloat16(vv);
      }
}

// ---------- K4: out = LN(attn @ vpw + q); 16 rows x 256 cols per block ----------
__global__ __launch_bounds__(256) void k_avln(const bf16* __restrict__ attn,
                                              const bf16* __restrict__ vpwt,
                                              const float* __restrict__ qres,
                                              const int* __restrict__ lens,
                                              const float* __restrict__ gam,
                                              const float* __restrict__ bet,
                                              float* __restrict__ outp)
{
  __shared__ bf16 smem[17408];  // 2KB A + 32KB B (single-buffer)
  const int tid = threadIdx.x, lane = tid & 63, wave = tid >> 6;
  // grid 512 flat; swizzle so batch ~ XCD
  const int flat = blockIdx.x;
  const int lid  = (flat & 7) * 64 + (flat >> 3);
  const int b = lid >> 6, bx = lid & 63;
  const int iBase = bx * 16;
  const int Keff = (lens[b] + 63) & ~63;
  const bf16* A  = attn + (size_t)b * SL * SL + (size_t)iBase * SL;
  const bf16* Bm = vpwt + (size_t)b * DD * SL;
  f32x4 acc[4] = {};
  for (int k0 = 0; k0 < Keff; k0 += 64) {
    stage16(A + k0, SL, smem, tid);
    stage_t<256>(Bm + k0, SL, smem + 1024, tid);
    __syncthreads();
    compute_16x256(smem, smem + 1024, lane, wave, acc);
    __syncthreads();
  }
  // epilogue: add residual, row-wise LN over D=256 (4 waves x 64-col slices)
  const int n15 = lane & 15, quad = lane >> 4;
  const int wc = wave << 6;
  float val[4][4];
  float sS_p[4], sQ_p[4];
#pragma unroll
  for (int r = 0; r < 4; ++r) {
    const size_t grow = (size_t)b * SL + iBase + quad * 4 + r;
    float s = 0.f, ss = 0.f;
#pragma unroll
    for (int tj = 0; tj < 4; ++tj) {
      const int col = wc + tj * 16 + n15;
      float vv = acc[tj][r] + qres[grow * DD + col];
      val[tj][r] = vv;
      s += vv; ss += vv * vv;
    }
    sS_p[r] = s; sQ_p[r] = ss;
  }
  // reduce across the 16 lanes of each quad
#pragma unroll
  for (int o = 8; o > 0; o >>= 1)
#pragma unroll
    for (int r = 0; r < 4; ++r) {
      sS_p[r] += __shfl_xor(sS_p[r], o, 64);
      sQ_p[r] += __shfl_xor(sQ_p[r], o, 64);
    }
  // cross-wave: 4 waves each contribute a 64-col partial per row (16 rows)
  float* sS = (float*)smem;          // safe: all LDS reads done (barrier above)
  float* sQ = sS + 4 * 16;
  if (n15 == 0) {
#pragma unroll
    for (int r = 0; r < 4; ++r) {
      const int rloc = quad * 4 + r;
      sS[wave * 16 + rloc] = sS_p[r];
      sQ[wave * 16 + rloc] = sQ_p[r];
    }
  }
  __syncthreads();
#pragma unroll
  for (int r = 0; r < 4; ++r) {
    const int rloc = quad * 4 + r;
    const float s  = sS[rloc] + sS[16 + rloc] + sS[32 + rloc] + sS[48 + rloc];
    const float ss = sQ[rloc] + sQ[16 + rloc] + sQ[32 + rloc] + sQ[48 + rloc];
    const float mean = s * (1.f / DD);
    const float var  = ss * (1.f / DD) - mean * mean;
    const float rstd = rsqrtf(var + 1e-6f);
    const size_t grow = (size_t)b * SL + iBase + rloc;
#pragma unroll
    for (int tj = 0; tj < 4; ++tj) {
      const int col = wc + tj * 16 + n15;
      const float y = (val[tj][r] - mean) * rstd * gam[col] + bet[col];
      outp[grow * DD + col] = y;
    }
  }
}

extern "C" void kernel_launch(void* const* d_in, const int* in_sizes, int n_in,
                              void* d_out, int out_size, void* d_ws, size_t ws_size,
                              hipStream_t stream)
{
  const float* q    = (const float*)d_in[0];
  const float* k    = (const float*)d_in[1];
  const float* v    = (const float*)d_in[2];
  const float* x    = (const float*)d_in[3];
  const int*  lens  = (const int*)d_in[4];
  const float* wqs  = (const float*)d_in[5];
  const float* wks  = (const float*)d_in[6];
  const float* wvs  = (const float*)d_in[7];
  const float* wqs2 = (const float*)d_in[8];
  const float* wks2 = (const float*)d_in[9];
  const float* wfc  = (const float*)d_in[10];
  const float* fi   = (const float*)d_in[11];
  const float* gam  = (const float*)d_in[12];
  const float* bet  = (const float*)d_in[13];

  char* w = (char*)d_ws;
  const size_t MB = 1u << 20;
  bf16* qq    = (bf16*)(w + 0 * MB);    // 8MB: cols 0-255 qp, 256-511 q2f
  bf16* kk    = (bf16*)(w + 8 * MB);    // 8MB: cols 0-255 kp, 256-511 k2f
  bf16* vpwt  = (bf16*)(w + 16 * MB);   // 4MB [b][d][l]  (vpw = v @ Wc^T)
  bf16* q2t   = (bf16*)(w + 20 * MB);   // 4MB [b][d][l]
  bf16* k2t   = (bf16*)(w + 24 * MB);   // 4MB [b][d][l]
  bf16* fa    = (bf16*)(w + 28 * MB);   // 16MB; reused as attn_b16 after k_famul
  bf16* attn_b16 = fa;
  float* Wc   = (float*)(w + 44 * MB);  // 256KB

  float* outp  = (float*)d_out;                       // (B,L,D) f32
  float* attnp = outp + (size_t)NB * SL * DD;         // (B,L,L) f32
  (void)wvs;

  dim3 blk(256);
  hipLaunchKernelGGL(k_fawc, dim3(NB * 128 + 64), blk, 0, stream,
                     x, fi, lens, wfc, wvs, fa, Wc);
  hipLaunchKernelGGL(k_proj,  dim3(64, 2, 5),  blk, 0, stream,
                     q, k, v, wqs, wks, Wc, wqs2, wks2, qq, kk, vpwt, q2t, k2t);
  hipLaunchKernelGGL(k_famul, dim3(512),       blk, 0, stream, fa, q2t, k2t, lens, qq, kk);
  hipLaunchKernelGGL(k_attn,  dim3(1024),      blk, 0, stream,
                     qq, kk, lens, attnp, attn_b16);
  hipLaunchKernelGGL(k_avln,  dim3(512),       blk, 0, stream,
                     attn_b16, vpwt, q, lens, gam, bet, outp);
}

// Round 4
// 181.967 us; speedup vs baseline: 1.0471x; 1.0471x over previous
//
#include <hip/hip_runtime.h>
#include <hip/hip_bf16.h>
#include <math.h>

typedef __hip_bfloat16 bf16;
typedef __bf16 bf16x8 __attribute__((ext_vector_type(8)));
typedef float  f32x4  __attribute__((ext_vector_type(4)));

#define NB 8
#define SL 1024
#define DD 256
#define NF 11
#define RPB 8

#define AS_G __attribute__((address_space(1)))
#define AS_L __attribute__((address_space(3)))

// ---------- fragment loaders ----------
__device__ __forceinline__ bf16x8 ldfrag(const bf16* p) {
  return *reinterpret_cast<const bf16x8*>(p);
}
__device__ __forceinline__ bf16x8 ldfrag(const float* p) {
  const float4 a = *reinterpret_cast<const float4*>(p);
  const float4 b = *reinterpret_cast<const float4*>(p + 4);
  bf16x8 r;
  r[0] = (__bf16)a.x; r[1] = (__bf16)a.y; r[2] = (__bf16)a.z; r[3] = (__bf16)a.w;
  r[4] = (__bf16)b.x; r[5] = (__bf16)b.y; r[6] = (__bf16)b.z; r[7] = (__bf16)b.w;
  return r;
}
__device__ __forceinline__ unsigned short us(float f) {
  bf16 h = __float2bfloat16(f);
  return *reinterpret_cast<unsigned short*>(&h);
}
__device__ __forceinline__ float tanh_fast(float x) {
  return 1.f - 2.f / (__expf(2.f * x) + 1.f);
}

// ---------- stage R rows x 64 k into XOR-swizzled LDS ----------
// f32 source: sync VGPR convert
template<int R>
__device__ __forceinline__ void stage_t(const float* __restrict__ g, int ld,
                                        bf16* __restrict__ s, int tid) {
#pragma unroll
  for (int it = 0; it < R / 32; ++it) {
    const int cid = it * 256 + tid;
    const int row = cid >> 3, c16 = cid & 7;
    bf16x8 v = ldfrag(g + (size_t)row * ld + c16 * 8);
    *reinterpret_cast<bf16x8*>(s + row * 64 + ((c16 ^ (row & 7)) << 3)) = v;
  }
}
// bf16 source: async global_load_lds, swizzle folded into source addr
template<int R>
__device__ __forceinline__ void stage_t(const bf16* __restrict__ g, int ld,
                                        bf16* __restrict__ s, int tid) {
  const int wbase = tid & ~63;
#pragma unroll
  for (int it = 0; it < R / 32; ++it) {
    const int cid = it * 256 + tid;
    const int row = cid >> 3, sc = cid & 7;
    const int c16 = sc ^ (row & 7);
    const bf16* src = g + (size_t)row * ld + c16 * 8;
    bf16* dst = s + (size_t)(it * 256 + wbase) * 8;
    __builtin_amdgcn_global_load_lds((const AS_G void*)src, (AS_L void*)dst, 16, 0, 0);
  }
}

// ---------- compute: 128x128 tile, 4 waves (2x2), each wave 64x64 ----------
__device__ __forceinline__ void compute_128x128(const bf16* __restrict__ sA,
                                                const bf16* __restrict__ sB,
                                                int lane, int wave, f32x4 acc[4][4]) {
  const int n15 = lane & 15, quad = lane >> 4;
  const int wr = (wave >> 1) << 6, wc = (wave & 1) << 6;
#pragma unroll
  for (int kc = 0; kc < 2; ++kc) {
    const int c16 = kc * 4 + quad;
    bf16x8 aF[4], bF[4];
#pragma unroll
    for (int t = 0; t < 4; ++t) {
      const int ra = wr + t * 16 + n15;
      aF[t] = *reinterpret_cast<const bf16x8*>(sA + ra * 64 + ((c16 ^ (ra & 7)) << 3));
      const int rb = wc + t * 16 + n15;
      bF[t] = *reinterpret_cast<const bf16x8*>(sB + rb * 64 + ((c16 ^ (rb & 7)) << 3));
    }
#pragma unroll
    for (int ti = 0; ti < 4; ++ti)
#pragma unroll
      for (int tj = 0; tj < 4; ++tj)
        acc[ti][tj] = __builtin_amdgcn_mfma_f32_16x16x32_bf16(aF[ti], bF[tj], acc[ti][tj], 0, 0, 0);
  }
}

// ---------- compute: 32x256 tile, 4 waves (1x4), each wave 32x64 ----------
__device__ __forceinline__ void compute_32x256(const bf16* __restrict__ sA,
                                               const bf16* __restrict__ sB,
                                               int lane, int wave, f32x4 acc[2][4]) {
  const int n15 = lane & 15, quad = lane >> 4;
  const int wc = wave << 6;
#pragma unroll
  for (int kc = 0; kc < 2; ++kc) {
    const int c16 = kc * 4 + quad;
    bf16x8 aF[2], bF[4];
#pragma unroll
    for (int t = 0; t < 2; ++t) {
      const int ra = t * 16 + n15;
      aF[t] = *reinterpret_cast<const bf16x8*>(sA + ra * 64 + ((c16 ^ (ra & 7)) << 3));
    }
#pragma unroll
    for (int t = 0; t < 4; ++t) {
      const int rb = wc + t * 16 + n15;
      bF[t] = *reinterpret_cast<const bf16x8*>(sB + rb * 64 + ((c16 ^ (rb & 7)) << 3));
    }
#pragma unroll
    for (int ti = 0; ti < 2; ++ti)
#pragma unroll
      for (int tj = 0; tj < 4; ++tj)
        acc[ti][tj] = __builtin_amdgcn_mfma_f32_16x16x32_bf16(aF[ti], bF[tj], acc[ti][tj], 0, 0, 0);
  }
}

// ---------- GEMM driver: C(128x128) += A(128xK) * B(128xK)^T ----------
// double-buffered LDS (2 x 32KB), prefetch next K-tile before compute,
// single barrier per K-step.
template<typename TA, typename TB>
__device__ __forceinline__ void gemm_128x128(const TA* __restrict__ A, int lda,
                                             const TB* __restrict__ B, int ldb, int K,
                                             bf16* s, int tid, f32x4 acc[4][4]) {
  const int lane = tid & 63, wave = tid >> 6;
  stage_t<128>(A, lda, s, tid);
  stage_t<128>(B, ldb, s + 8192, tid);
  int cur = 0;
  __syncthreads();
  for (int k0 = 0; k0 < K; k0 += 64) {
    bf16* sc0 = s + cur * 16384;
    if (k0 + 64 < K) {
      bf16* sn = s + (cur ^ 1) * 16384;
      stage_t<128>(A + k0 + 64, lda, sn, tid);
      stage_t<128>(B + k0 + 64, ldb, sn + 8192, tid);
    }
    compute_128x128(sc0, sc0 + 8192, lane, wave, acc);
    __syncthreads();
    cur ^= 1;
  }
}

__device__ __forceinline__ float wred_sum(float v) {
#pragma unroll
  for (int o = 32; o > 0; o >>= 1) v += __shfl_xor(v, o, 64);
  return v;
}

// ---------- K0: fused {5 projections} + {feature-affinity softmax} ----------
// blocks 0..639: proj (z = bid>>7); blocks 640..1663: fa rows
// z==2 now computes plain vp = v @ wvs^T (w_fc applied later in k_avln).
__global__ __launch_bounds__(256) void k_fp(
    const float* __restrict__ q, const float* __restrict__ k, const float* __restrict__ v,
    const float* __restrict__ x, const float* __restrict__ fi_g,
    const int* __restrict__ lens,
    const float* __restrict__ wqs, const float* __restrict__ wks,
    const float* __restrict__ wvs, const float* __restrict__ wqs2,
    const float* __restrict__ wks2,
    bf16* __restrict__ qq, bf16* __restrict__ kk,
    bf16* __restrict__ vpt, bf16* __restrict__ q2t, bf16* __restrict__ k2t,
    bf16* __restrict__ fa)
{
  __shared__ __align__(16) char pool[65536];
  const int tid = threadIdx.x, lane = tid & 63, wave = tid >> 6;
  const int bid = blockIdx.x;
  if (bid < 640) {
    // ---------------- projection part ----------------
    bf16* smem = (bf16*)pool;
    const int z = bid >> 7, sub = bid & 127;
    const int rowBase = (sub & 63) * 128;
    const int colBase = (sub >> 6) * 128;
    const float* A = (z == 2) ? v : ((z == 1 || z == 4) ? k : q);
    const float* W = (z == 0) ? wqs : (z == 1) ? wks : (z == 2) ? wvs : (z == 3) ? wqs2 : wks2;
    f32x4 acc[4][4] = {};
    gemm_128x128(A + (size_t)rowBase * DD, DD, W + (size_t)colBase * DD, DD, DD, smem, tid, acc);
    const int n15 = lane & 15, quad = lane >> 4;
    const int wr = (wave >> 1) << 6, wc = (wave & 1) << 6;
    if (z <= 1) {
      bf16* O = (z == 0) ? qq : kk;
#pragma unroll
      for (int ti = 0; ti < 4; ++ti)
#pragma unroll
        for (int tj = 0; tj < 4; ++tj)
#pragma unroll
          for (int r = 0; r < 4; ++r) {
            int row = rowBase + wr + ti * 16 + quad * 4 + r;
            int col = colBase + wc + tj * 16 + n15;
            O[(size_t)row * 512 + col] = __float2bfloat16(acc[ti][tj][r]);
          }
    } else {
      bf16* O = (z == 2) ? vpt : (z == 3) ? q2t : k2t;
      const int bb = rowBase >> 10, rowInB = rowBase & 1023;
#pragma unroll
      for (int ti = 0; ti < 4; ++ti)
#pragma unroll
        for (int tj = 0; tj < 4; ++tj) {
          int l0  = rowInB + wr + ti * 16 + quad * 4;
          int col = colBase + wc + tj * 16 + n15;
          ushort4 pk = make_ushort4(us(acc[ti][tj][0]), us(acc[ti][tj][1]),
                                    us(acc[ti][tj][2]), us(acc[ti][tj][3]));
          *reinterpret_cast<ushort4*>(&O[((size_t)bb * DD + col) * SL + l0]) = pk;
        }
    }
    return;
  }
  // ---------------- feature-affinity part ----------------
  float* sx = (float*)pool;                    // 45056 B
  float* sredS = (float*)(pool + 45056);       // 4*RPB floats
  const int fid = bid - 640;
  const int b  = fid >> 7;
  const int i0 = (fid & 127) * RPB;
  {
    const float4* src = reinterpret_cast<const float4*>(x + (size_t)b * SL * NF);
    float4* dst = reinterpret_cast<float4*>(sx);
#pragma unroll
    for (int it = 0; it < 11; ++it) dst[it * 256 + tid] = src[it * 256 + tid];
  }
  float fiv[NF];
#pragma unroll
  for (int f = 0; f < NF; ++f) fiv[f] = fi_g[f];
  const int len = lens[b];
  __syncthreads();
  float xi[RPB][NF];
#pragma unroll
  for (int i = 0; i < RPB; ++i)
#pragma unroll
    for (int f = 0; f < NF; ++f) xi[i][f] = sx[(i0 + i) * NF + f];
  float e[RPB][4];
  float ps[RPB];
#pragma unroll
  for (int i = 0; i < RPB; ++i) ps[i] = 0.f;
#pragma unroll
  for (int t = 0; t < 4; ++t) {
    const int j = tid + t * 256;
    const bool valid = (t < 2) || (j < len);
    float xj[NF];
#pragma unroll
    for (int f = 0; f < NF; ++f) xj[f] = sx[j * NF + f];
#pragma unroll
    for (int i = 0; i < RPB; ++i) {
      float a = 0.f;
#pragma unroll
      for (int f = 0; f < NF; ++f) a += fabsf(xi[i][f] - xj[f]) * fiv[f];
      float ev = valid ? __expf(a) : 0.f;
      e[i][t] = ev;
      ps[i] += ev;
    }
  }
#pragma unroll
  for (int i = 0; i < RPB; ++i) {
    float wsv = wred_sum(ps[i]);
    if ((tid & 63) == 0) sredS[wave * RPB + i] = wsv;
  }
  __syncthreads();
  bf16* out = fa + (size_t)b * SL * SL + (size_t)i0 * SL;
#pragma unroll
  for (int i = 0; i < RPB; ++i) {
    const float inv = 1.f / (sredS[0 * RPB + i] + sredS[1 * RPB + i] +
                             sredS[2 * RPB + i] + sredS[3 * RPB + i]);
#pragma unroll
    for (int t = 0; t < 4; ++t)
      out[(size_t)i * SL + tid + t * 256] = __float2bfloat16(e[i][t] * inv);
  }
}

// ---------- K1: q2f/k2f = fa @ {q2,k2} -> qq/kk cols 256..511 ----------
__global__ __launch_bounds__(256) void k_famul(const bf16* __restrict__ fa,
                                               const bf16* __restrict__ q2t,
                                               const bf16* __restrict__ k2t,
                                               const int* __restrict__ lens,
                                               bf16* __restrict__ qq,
                                               bf16* __restrict__ kk)
{
  __shared__ bf16 smem[32768];
  const int tid = threadIdx.x, lane = tid & 63, wave = tid >> 6;
  // grid (8,2,16); swizzle so batch ~ XCD
  const int flat = blockIdx.x + 8 * blockIdx.y + 16 * blockIdx.z;
  const int lid  = (flat & 7) * 32 + (flat >> 3);
  const int bx = lid & 7, by = (lid >> 3) & 1, bz = lid >> 4;
  const int b = bz >> 1, which = bz & 1;
  const int iBase = bx * 128, dBase = by * 128;
  const int Keff = (lens[b] + 63) & ~63;
  const bf16* A  = fa + (size_t)b * SL * SL + (size_t)iBase * SL;
  const bf16* Bm = (which ? k2t : q2t) + (size_t)b * DD * SL + (size_t)dBase * SL;
  f32x4 acc[4][4] = {};
  gemm_128x128(A, SL, Bm, SL, Keff, smem, tid, acc);
  bf16* O = (which ? kk : qq) + (size_t)b * SL * 512 + 256;
  const int n15 = lane & 15, quad = lane >> 4;
  const int wr = (wave >> 1) << 6, wc = (wave & 1) << 6;
#pragma unroll
  for (int ti = 0; ti < 4; ++ti)
#pragma unroll
    for (int tj = 0; tj < 4; ++tj)
#pragma unroll
      for (int r = 0; r < 4; ++r)
        O[(size_t)(iBase + wr + ti * 16 + quad * 4 + r) * 512 +
          dBase + wc + tj * 16 + n15] = __float2bfloat16(acc[ti][tj][r]);
}

// ---------- K2: attn = tanh(mask(qq.kk^T/16)), K=512; dual store ----------
__global__ __launch_bounds__(256) void k_attn(const bf16* __restrict__ qq,
                                              const bf16* __restrict__ kk,
                                              const int* __restrict__ lens,
                                              float* __restrict__ attn_f32,
                                              bf16* __restrict__ attn_b16)
{
  __shared__ bf16 smem[32768];
  const int tid = threadIdx.x, lane = tid & 63, wave = tid >> 6;
  // grid (8,8,8); swizzle so batch ~ XCD
  const int flat = blockIdx.x + 8 * blockIdx.y + 64 * blockIdx.z;
  const int lid  = (flat & 7) * 64 + (flat >> 3);
  const int bx = lid & 7, by = (lid >> 3) & 7, bz = lid >> 6;
  const int b = bz;
  const int iBase = bx * 128, jBase = by * 128;
  const int len = lens[b];
  if (jBase >= len) {
    const int r = tid >> 1, ch = (tid & 1) * 64;
    float* pf = attn_f32 + (size_t)b * SL * SL + (size_t)(iBase + r) * SL + jBase + ch;
    bf16*  pb = attn_b16 + (size_t)b * SL * SL + (size_t)(iBase + r) * SL + jBase + ch;
    const float4 z4 = make_float4(0.f, 0.f, 0.f, 0.f);
    const uint4  zb = make_uint4(0u, 0u, 0u, 0u);
#pragma unroll
    for (int i = 0; i < 16; ++i) *reinterpret_cast<float4*>(pf + i * 4) = z4;
#pragma unroll
    for (int i = 0; i < 8; ++i)  *reinterpret_cast<uint4*>(pb + i * 8) = zb;
    return;
  }
  f32x4 acc[4][4] = {};
  gemm_128x128(qq + ((size_t)b * SL + iBase) * 512, 512,
               kk + ((size_t)b * SL + jBase) * 512, 512, 512, smem, tid, acc);
  const int n15 = lane & 15, quad = lane >> 4;
  const int wr = (wave >> 1) << 6, wc = (wave & 1) << 6;
#pragma unroll
  for (int ti = 0; ti < 4; ++ti)
#pragma unroll
    for (int tj = 0; tj < 4; ++tj)
#pragma unroll
      for (int r = 0; r < 4; ++r) {
        int i = iBase + wr + ti * 16 + quad * 4 + r;
        int j = jBase + wc + tj * 16 + n15;
        float vv = (j < len) ? tanh_fast(acc[ti][tj][r] * (1.f / 16.f)) : 0.f;
        size_t idx = (size_t)b * SL * SL + (size_t)i * SL + j;
        attn_f32[idx] = vv;
        attn_b16[idx] = __float2bfloat16(vv);
      }
}

// ---------- K3: out = LN( (attn @ vp) @ wfc^T + q ); 32 rows x 256 cols ----------
__global__ __launch_bounds__(256) void k_avln(const bf16* __restrict__ attn,
                                              const bf16* __restrict__ vpt,
                                              const float* __restrict__ qres,
                                              const float* __restrict__ wfc,
                                              const int* __restrict__ lens,
                                              const float* __restrict__ gam,
                                              const float* __restrict__ bet,
                                              float* __restrict__ outp)
{
  __shared__ bf16 smem[36864];  // 72KB
  const int tid = threadIdx.x, lane = tid & 63, wave = tid >> 6;
  // grid 256 flat; swizzle so batch ~ XCD
  const int flat = blockIdx.x;
  const int lid  = (flat & 7) * 32 + (flat >> 3);
  const int b = lid >> 5, bx = lid & 31;
  const int iBase = bx * 32;
  const int Keff = (lens[b] + 63) & ~63;
  const bf16* A  = attn + (size_t)b * SL * SL + (size_t)iBase * SL;
  const bf16* Bm = vpt + (size_t)b * DD * SL;
  f32x4 acc[2][4] = {};
  {
    stage_t<32>(A, SL, smem, tid);
    stage_t<256>(Bm, SL, smem + 2048, tid);
    int cur = 0;
    __syncthreads();
    for (int k0 = 0; k0 < Keff; k0 += 64) {
      bf16* sc = smem + cur * 18432;
      if (k0 + 64 < Keff) {
        bf16* sn = smem + (cur ^ 1) * 18432;
        stage_t<32>(A + k0 + 64, SL, sn, tid);
        stage_t<256>(Bm + k0 + 64, SL, sn + 2048, tid);
      }
      compute_32x256(sc, sc + 2048, lane, wave, acc);
      __syncthreads();
      cur ^= 1;
    }
  }
  const int n15 = lane & 15, quad = lane >> 4;
  // ---- epilogue GEMM: out1 = Y @ wfc^T, Y = attn@vp (in acc) ----
  bf16* sY  = smem;           // 32 rows x 256 cols (4 swizzled 64-blocks), 16KB
  bf16* sB2 = smem + 8192;    // 256 x 64 staged wfc slice, 32KB
#pragma unroll
  for (int ti = 0; ti < 2; ++ti)
#pragma unroll
    for (int tj = 0; tj < 4; ++tj)
#pragma unroll
      for (int r = 0; r < 4; ++r) {
        const int row = ti * 16 + quad * 4 + r;
        const int cc  = tj * 16 + n15;
        sY[wave * 2048 + row * 64 + (((cc >> 3) ^ (row & 7)) << 3) + (cc & 7)] =
            __float2bfloat16(acc[ti][tj][r]);
      }
  stage_t<256>(wfc, DD, sB2, tid);
  __syncthreads();
  f32x4 acc2[2][4] = {};
#pragma unroll 1
  for (int kb = 0; kb < 4; ++kb) {
    compute_32x256(sY + kb * 2048, sB2, lane, wave, acc2);
    __syncthreads();
    if (kb < 3) {
      stage_t<256>(wfc + (kb + 1) * 64, DD, sB2, tid);
      __syncthreads();
    }
  }
  // ---- residual + LN over D=256 (4 waves x 64-col slices) ----
  const int wcol = wave << 6;
  float val[2][4][4];
  float sS_p[2][4], sQ_p[2][4];
#pragma unroll
  for (int ti = 0; ti < 2; ++ti)
#pragma unroll
    for (int r = 0; r < 4; ++r) {
      const size_t grow = (size_t)b * SL + iBase + ti * 16 + quad * 4 + r;
      float s = 0.f, ss = 0.f;
#pragma unroll
      for (int tj = 0; tj < 4; ++tj) {
        const int col = wcol + tj * 16 + n15;
        float vv = acc2[ti][tj][r] + qres[grow * DD + col];
        val[ti][tj][r] = vv;
        s += vv; ss += vv * vv;
      }
      sS_p[ti][r] = s; sQ_p[ti][r] = ss;
    }
#pragma unroll
  for (int o = 8; o > 0; o >>= 1)
#pragma unroll
    for (int ti = 0; ti < 2; ++ti)
#pragma unroll
      for (int r = 0; r < 4; ++r) {
        sS_p[ti][r] += __shfl_xor(sS_p[ti][r], o, 64);
        sQ_p[ti][r] += __shfl_xor(sQ_p[ti][r], o, 64);
      }
  float* sS = (float*)smem;   // safe: epilogue GEMM fully barriered above
  float* sQ = sS + 4 * 32;
  if (n15 == 0) {
#pragma unroll
    for (int ti = 0; ti < 2; ++ti)
#pragma unroll
      for (int r = 0; r < 4; ++r) {
        const int rloc = ti * 16 + quad * 4 + r;
        sS[wave * 32 + rloc] = sS_p[ti][r];
        sQ[wave * 32 + rloc] = sQ_p[ti][r];
      }
  }
  __syncthreads();
#pragma unroll
  for (int ti = 0; ti < 2; ++ti)
#pragma unroll
    for (int r = 0; r < 4; ++r) {
      const int rloc = ti * 16 + quad * 4 + r;
      const float s  = sS[rloc] + sS[32 + rloc] + sS[64 + rloc] + sS[96 + rloc];
      const float ss = sQ[rloc] + sQ[32 + rloc] + sQ[64 + rloc] + sQ[96 + rloc];
      const float mean = s * (1.f / DD);
      const float var  = ss * (1.f / DD) - mean * mean;
      const float rstd = rsqrtf(var + 1e-6f);
      const size_t grow = (size_t)b * SL + iBase + rloc;
#pragma unroll
      for (int tj = 0; tj < 4; ++tj) {
        const int col = wcol + tj * 16 + n15;
        const float y = (val[ti][tj][r] - mean) * rstd * gam[col] + bet[col];
        outp[grow * DD + col] = y;
      }
    }
}

extern "C" void kernel_launch(void* const* d_in, const int* in_sizes, int n_in,
                              void* d_out, int out_size, void* d_ws, size_t ws_size,
                              hipStream_t stream)
{
  const float* q    = (const float*)d_in[0];
  const float* k    = (const float*)d_in[1];
  const float* v    = (const float*)d_in[2];
  const float* x    = (const float*)d_in[3];
  const int*  lens  = (const int*)d_in[4];
  const float* wqs  = (const float*)d_in[5];
  const float* wks  = (const float*)d_in[6];
  const float* wvs  = (const float*)d_in[7];
  const float* wqs2 = (const float*)d_in[8];
  const float* wks2 = (const float*)d_in[9];
  const float* wfc  = (const float*)d_in[10];
  const float* fi   = (const float*)d_in[11];
  const float* gam  = (const float*)d_in[12];
  const float* bet  = (const float*)d_in[13];

  char* w = (char*)d_ws;
  const size_t MB = 1u << 20;
  bf16* qq    = (bf16*)(w + 0 * MB);    // 8MB: cols 0-255 qp, 256-511 q2f
  bf16* kk    = (bf16*)(w + 8 * MB);    // 8MB: cols 0-255 kp, 256-511 k2f
  bf16* vpt   = (bf16*)(w + 16 * MB);   // 4MB [b][d][l]  (vp = v @ wvs^T)
  bf16* q2t   = (bf16*)(w + 20 * MB);   // 4MB [b][d][l]
  bf16* k2t   = (bf16*)(w + 24 * MB);   // 4MB [b][d][l]
  bf16* fa    = (bf16*)(w + 28 * MB);   // 16MB; reused as attn_b16 after k_famul
  bf16* attn_b16 = fa;

  float* outp  = (float*)d_out;                       // (B,L,D) f32
  float* attnp = outp + (size_t)NB * SL * DD;         // (B,L,L) f32

  dim3 blk(256);
  hipLaunchKernelGGL(k_fp,    dim3(640 + NB * 128), blk, 0, stream,
                     q, k, v, x, fi, lens, wqs, wks, wvs, wqs2, wks2,
                     qq, kk, vpt, q2t, k2t, fa);
  hipLaunchKernelGGL(k_famul, dim3(8, 2, 16),  blk, 0, stream, fa, q2t, k2t, lens, qq, kk);
  hipLaunchKernelGGL(k_attn,  dim3(8, 8, 8),   blk, 0, stream,
                     qq, kk, lens, attnp, attn_b16);
  hipLaunchKernelGGL(k_avln,  dim3(256),       blk, 0, stream,
                     attn_b16, vpt, q, wfc, lens, gam, bet, outp);
}